// Round 1
// baseline (1066.756 us; speedup 1.0000x reference)
//
#include <hip/hip_runtime.h>
#include <math.h>

#define DIM 64
#define CODES 512
#define TOKENS 262144
#define XELEMS 16777216

#define DECAYF 0.99f
#define OMDECAY 0.01f
#define EPSF 1e-5f

// workspace float offsets
#define WS_CNORM 0
#define WS_NI    512
#define WS_EOFX  1024           // 64*512 floats
#define WS_LOSS  33792
#define WS_ET    33824          // 512*64 floats (transposed embedding)

// output float offsets (outputs concatenated in reference return order)
#define OFF_Q    0
#define OFF_QL   16777216
#define OFF_IDX  16777217
#define OFF_CL   17039361
#define OFF_ENEW 17039362
#define OFF_NNEW 17072130
#define OFF_MNEW 17072642

// Transpose embedding [DIM][CODES] -> eT [CODES][DIM] and compute per-code sq norms.
__global__ __launch_bounds__(512) void vq_prep(const float* __restrict__ emb,
                                               float* __restrict__ ws) {
  int c = threadIdx.x;  // one thread per code
  float* eT = ws + WS_ET;
  float a0 = 0.f, a1 = 0.f, a2 = 0.f, a3 = 0.f;
#pragma unroll
  for (int d = 0; d < DIM; d += 4) {
    float v0 = emb[(d + 0) * CODES + c];
    float v1 = emb[(d + 1) * CODES + c];
    float v2 = emb[(d + 2) * CODES + c];
    float v3 = emb[(d + 3) * CODES + c];
    eT[c * DIM + d + 0] = v0;
    eT[c * DIM + d + 1] = v1;
    eT[c * DIM + d + 2] = v2;
    eT[c * DIM + d + 3] = v3;
    a0 = fmaf(v0, v0, a0);
    a1 = fmaf(v1, v1, a1);
    a2 = fmaf(v2, v2, a2);
    a3 = fmaf(v3, v3, a3);
  }
  ws[WS_CNORM + c] = (a0 + a1) + (a2 + a3);
}

// One thread per token: argmin over 512 codes, write quantize+index,
// accumulate ni/eofx/loss.
__global__ __launch_bounds__(256) void vq_main(
    const float* __restrict__ x,
    const float* __restrict__ cnorm,
    const float* __restrict__ eT,
    float* __restrict__ ni,
    float* __restrict__ eofx,
    float* __restrict__ loss_sum,
    float* __restrict__ q_out,
    float* __restrict__ idx_out) {
  int t = blockIdx.x * 256 + threadIdx.x;

  // load this token's 64 features into registers
  float xr[DIM];
  {
    const float4* xp = (const float4*)(x + (size_t)t * DIM);
#pragma unroll
    for (int i = 0; i < DIM / 4; ++i) {
      float4 v = xp[i];
      xr[4 * i + 0] = v.x;
      xr[4 * i + 1] = v.y;
      xr[4 * i + 2] = v.z;
      xr[4 * i + 3] = v.w;
    }
  }

  // ||x||^2 (constant per token; kept to mimic reference arithmetic)
  float s0 = 0.f, s1 = 0.f, s2 = 0.f, s3 = 0.f;
#pragma unroll
  for (int d = 0; d < DIM; d += 4) {
    s0 = fmaf(xr[d + 0], xr[d + 0], s0);
    s1 = fmaf(xr[d + 1], xr[d + 1], s1);
    s2 = fmaf(xr[d + 2], xr[d + 2], s2);
    s3 = fmaf(xr[d + 3], xr[d + 3], s3);
  }
  float sx = (s0 + s1) + (s2 + s3);

  float best = 3.4e38f;
  int bi = 0;
  for (int c = 0; c < CODES; ++c) {
    const float* ec = eT + c * DIM;  // wave-uniform address -> s_load
    float d0 = 0.f, d1 = 0.f, d2 = 0.f, d3 = 0.f;
#pragma unroll
    for (int d = 0; d < DIM; d += 4) {
      d0 = fmaf(xr[d + 0], ec[d + 0], d0);
      d1 = fmaf(xr[d + 1], ec[d + 1], d1);
      d2 = fmaf(xr[d + 2], ec[d + 2], d2);
      d3 = fmaf(xr[d + 3], ec[d + 3], d3);
    }
    float dot = (d0 + d1) + (d2 + d3);
    float dist = (sx - 2.0f * dot) + cnorm[c];
    if (dist < best) {  // strict < keeps first min, matching jnp.argmin
      best = dist;
      bi = c;
    }
  }

  idx_out[t] = (float)bi;

  // gather quantize row, write out, accumulate quantization loss
  const float* eb = eT + bi * DIM;  // per-lane (divergent) address
  float l0 = 0.f, l1 = 0.f, l2 = 0.f, l3 = 0.f;
  float4* qp = (float4*)(q_out + (size_t)t * DIM);
#pragma unroll
  for (int d = 0; d < DIM; d += 4) {
    float4 q;
    q.x = eb[d + 0];
    q.y = eb[d + 1];
    q.z = eb[d + 2];
    q.w = eb[d + 3];
    qp[d / 4] = q;
    float e0 = xr[d + 0] - q.x;
    float e1 = xr[d + 1] - q.y;
    float e2 = xr[d + 2] - q.z;
    float e3 = xr[d + 3] - q.w;
    l0 = fmaf(e0, e0, l0);
    l1 = fmaf(e1, e1, l1);
    l2 = fmaf(e2, e2, l2);
    l3 = fmaf(e3, e3, l3);
  }
  float lsum = (l0 + l1) + (l2 + l3);

  // segment-sum accumulators
  atomicAdd(&ni[bi], 1.0f);
#pragma unroll
  for (int d = 0; d < DIM; ++d) {
    atomicAdd(&eofx[d * CODES + bi], xr[d]);
  }

  // per-wave loss reduction -> one atomic per wave
#pragma unroll
  for (int off = 32; off > 0; off >>= 1) lsum += __shfl_down(lsum, off, 64);
  if ((threadIdx.x & 63) == 0) atomicAdd(loss_sum, lsum);
}

// EMA update + losses. One block, 512 threads (one per code).
__global__ __launch_bounds__(512) void vq_final(const float* __restrict__ Nin,
                                                const float* __restrict__ Min,
                                                const float* __restrict__ ws,
                                                float* __restrict__ out) {
  __shared__ float red[512];
  int c = threadIdx.x;
  float niv = ws[WS_NI + c];
  float Nn = Nin[c] * DECAYF + OMDECAY * niv;
  out[OFF_NNEW + c] = Nn;
  red[c] = Nn;
  __syncthreads();
#pragma unroll
  for (int s = 256; s > 0; s >>= 1) {
    if (c < s) red[c] += red[c + s];
    __syncthreads();
  }
  float n = red[0];
  float Nsm = (Nn + EPSF) / (n + (float)CODES * EPSF) * n;
  for (int d = 0; d < DIM; ++d) {
    float m = Min[d * CODES + c] * DECAYF + OMDECAY * ws[WS_EOFX + d * CODES + c];
    out[OFF_MNEW + d * CODES + c] = m;
    out[OFF_ENEW + d * CODES + c] = m / Nsm;  // true division to match reference
  }
  if (c == 0) {
    float l = ws[WS_LOSS] / (float)XELEMS;
    out[OFF_QL] = l;
    out[OFF_CL] = l;  // quant_loss == commitment_loss numerically
  }
}

extern "C" void kernel_launch(void* const* d_in, const int* in_sizes, int n_in,
                              void* d_out, int out_size, void* d_ws, size_t ws_size,
                              hipStream_t stream) {
  const float* x = (const float*)d_in[0];
  const float* emb = (const float*)d_in[1];
  const float* Nin = (const float*)d_in[2];
  const float* Min = (const float*)d_in[3];
  float* out = (float*)d_out;
  float* ws = (float*)d_ws;

  // zero the accumulator region (cnorm..loss); eT is fully overwritten by vq_prep
  hipMemsetAsync(d_ws, 0, (size_t)WS_ET * sizeof(float), stream);

  vq_prep<<<1, 512, 0, stream>>>(emb, ws);

  vq_main<<<TOKENS / 256, 256, 0, stream>>>(
      x, ws + WS_CNORM, ws + WS_ET, ws + WS_NI, ws + WS_EOFX, ws + WS_LOSS,
      out + OFF_Q, out + OFF_IDX);

  vq_final<<<1, 512, 0, stream>>>(Nin, Min, ws, out);
}

// Round 2
// 688.711 us; speedup vs baseline: 1.5489x; 1.5489x over previous
//
#include <hip/hip_runtime.h>
#include <math.h>

#define DIM 64
#define CODES 512
#define TOKENS 262144
#define XELEMS 16777216

#define DECAYF 0.99f
#define OMDECAY 0.01f
#define EPSF 1e-5f

// workspace float offsets
#define WS_CNORM 0            // 512
#define WS_NI    512          // 512
#define WS_EOFX  1024         // 64*512 = 32768 (contiguous after NI: [ni|eofx])
#define WS_LOSS  33792        // 1 (+pad)
#define WS_ET    33800        // 512*64 transposed embedding (16B aligned)
#define WS_IDX   66568        // 262144 int32 indices
#define WS_PART  328712       // P partials, each PART_STRIDE floats
#define PART_STRIDE 33280     // 512 ni + 32768 eofx

// output float offsets (outputs concatenated in reference return order)
#define OFF_Q    0
#define OFF_QL   16777216
#define OFF_IDX  16777217
#define OFF_CL   17039361
#define OFF_ENEW 17039362
#define OFF_NNEW 17072130
#define OFF_MNEW 17072642

// Transpose embedding [DIM][CODES] -> eT [CODES][DIM] and per-code sq norms.
__global__ __launch_bounds__(512) void vq_prep(const float* __restrict__ emb,
                                               float* __restrict__ ws) {
  int c = threadIdx.x;
  float* eT = ws + WS_ET;
  float a0 = 0.f, a1 = 0.f, a2 = 0.f, a3 = 0.f;
#pragma unroll
  for (int d = 0; d < DIM; d += 4) {
    float v0 = emb[(d + 0) * CODES + c];
    float v1 = emb[(d + 1) * CODES + c];
    float v2 = emb[(d + 2) * CODES + c];
    float v3 = emb[(d + 3) * CODES + c];
    eT[c * DIM + d + 0] = v0;
    eT[c * DIM + d + 1] = v1;
    eT[c * DIM + d + 2] = v2;
    eT[c * DIM + d + 3] = v3;
    a0 = fmaf(v0, v0, a0);
    a1 = fmaf(v1, v1, a1);
    a2 = fmaf(v2, v2, a2);
    a3 = fmaf(v3, v3, a3);
  }
  ws[WS_CNORM + c] = (a0 + a1) + (a2 + a3);
}

// One thread per token: argmin over 512 codes, write quantize + idx + loss.
// NO scattered global atomics (R1: they caused 470 MB of HBM RMW write-through).
__global__ __launch_bounds__(256) void vq_main(
    const float* __restrict__ x,
    const float* __restrict__ cnorm,
    const float* __restrict__ eT,
    float* __restrict__ loss_sum,
    float* __restrict__ q_out,
    float* __restrict__ idx_out,
    int* __restrict__ idx_int) {
  int t = blockIdx.x * 256 + threadIdx.x;

  float xr[DIM];
  {
    const float4* xp = (const float4*)(x + (size_t)t * DIM);
#pragma unroll
    for (int i = 0; i < DIM / 4; ++i) {
      float4 v = xp[i];
      xr[4 * i + 0] = v.x;
      xr[4 * i + 1] = v.y;
      xr[4 * i + 2] = v.z;
      xr[4 * i + 3] = v.w;
    }
  }

  float s0 = 0.f, s1 = 0.f, s2 = 0.f, s3 = 0.f;
#pragma unroll
  for (int d = 0; d < DIM; d += 4) {
    s0 = fmaf(xr[d + 0], xr[d + 0], s0);
    s1 = fmaf(xr[d + 1], xr[d + 1], s1);
    s2 = fmaf(xr[d + 2], xr[d + 2], s2);
    s3 = fmaf(xr[d + 3], xr[d + 3], s3);
  }
  float sx = (s0 + s1) + (s2 + s3);

  float best = 3.4e38f;
  int bi = 0;
  for (int c = 0; c < CODES; ++c) {
    const float* ec = eT + c * DIM;  // wave-uniform -> s_load stream
    float d0 = 0.f, d1 = 0.f, d2 = 0.f, d3 = 0.f;
#pragma unroll
    for (int d = 0; d < DIM; d += 4) {
      d0 = fmaf(xr[d + 0], ec[d + 0], d0);
      d1 = fmaf(xr[d + 1], ec[d + 1], d1);
      d2 = fmaf(xr[d + 2], ec[d + 2], d2);
      d3 = fmaf(xr[d + 3], ec[d + 3], d3);
    }
    float dot = (d0 + d1) + (d2 + d3);
    float dist = (sx - 2.0f * dot) + cnorm[c];
    if (dist < best) {  // strict <: first min, matches jnp.argmin
      best = dist;
      bi = c;
    }
  }

  idx_out[t] = (float)bi;
  idx_int[t] = bi;

  const float* eb = eT + bi * DIM;  // divergent gather, eT is L2-hot (128 KB)
  float l0 = 0.f, l1 = 0.f, l2 = 0.f, l3 = 0.f;
  float4* qp = (float4*)(q_out + (size_t)t * DIM);
#pragma unroll
  for (int d = 0; d < DIM; d += 4) {
    float4 q;
    q.x = eb[d + 0];
    q.y = eb[d + 1];
    q.z = eb[d + 2];
    q.w = eb[d + 3];
    qp[d / 4] = q;
    float e0 = xr[d + 0] - q.x;
    float e1 = xr[d + 1] - q.y;
    float e2 = xr[d + 2] - q.z;
    float e3 = xr[d + 3] - q.w;
    l0 = fmaf(e0, e0, l0);
    l1 = fmaf(e1, e1, l1);
    l2 = fmaf(e2, e2, l2);
    l3 = fmaf(e3, e3, l3);
  }
  float lsum = (l0 + l1) + (l2 + l3);
#pragma unroll
  for (int off = 32; off > 0; off >>= 1) lsum += __shfl_down(lsum, off, 64);
  if ((threadIdx.x & 63) == 0) atomicAdd(loss_sum, lsum);
}

// Segment sum with LDS privatization. Each block owns a contiguous token
// range; codes are processed in 4 quarters of 128 so the LDS tile is 32 KB.
// Flush per-block partials non-atomically to `dest` (partial slice), or with
// coalesced global atomics if aflush!=0 (small-ws fallback; dest=[ni|eofx]).
__global__ __launch_bounds__(256) void vq_segsum(
    const float* __restrict__ x,
    const int* __restrict__ idx,
    float* __restrict__ dest_base,
    int tokens_per_block,
    int part_stride,   // 0 for atomic-flush path
    int aflush) {
  __shared__ float lds_n[CODES];
  __shared__ float lds_e[DIM * 128];
  int p = blockIdx.x;
  int t0 = p * tokens_per_block;
  float* dest = dest_base + (size_t)p * part_stride;

  for (int i = threadIdx.x; i < CODES; i += 256) lds_n[i] = 0.f;

  for (int q = 0; q < 4; ++q) {
    for (int i = threadIdx.x; i < DIM * 128; i += 256) lds_e[i] = 0.f;
    __syncthreads();

    for (int tt = threadIdx.x; tt < tokens_per_block; tt += 256) {
      int t = t0 + tt;
      int bi = idx[t];
      if (q == 0) atomicAdd(&lds_n[bi], 1.0f);
      int cl = bi - q * 128;
      if (cl >= 0 && cl < 128) {
        const float4* xp = (const float4*)(x + (size_t)t * DIM);
#pragma unroll
        for (int i = 0; i < DIM / 4; ++i) {
          float4 v = xp[i];
          atomicAdd(&lds_e[(4 * i + 0) * 128 + cl], v.x);
          atomicAdd(&lds_e[(4 * i + 1) * 128 + cl], v.y);
          atomicAdd(&lds_e[(4 * i + 2) * 128 + cl], v.z);
          atomicAdd(&lds_e[(4 * i + 3) * 128 + cl], v.w);
        }
      }
    }
    __syncthreads();

    for (int i = threadIdx.x; i < DIM * 128; i += 256) {
      int d = i >> 7, cl = i & 127;
      float v = lds_e[i];
      int o = CODES + d * CODES + q * 128 + cl;
      if (aflush) {
        if (v != 0.f) atomicAdd(&dest[o], v);
      } else {
        dest[o] = v;
      }
    }
    __syncthreads();
  }

  for (int i = threadIdx.x; i < CODES; i += 256) {
    float v = lds_n[i];
    if (aflush) {
      if (v != 0.f) atomicAdd(&dest[i], v);
    } else {
      dest[i] = v;
    }
  }
}

// Deterministic reduction of P partials -> ws[WS_NI .. WS_NI+33280)
__global__ __launch_bounds__(256) void vq_reduce(const float* __restrict__ part,
                                                 float* __restrict__ ws,
                                                 int P) {
  int i = blockIdx.x * 256 + threadIdx.x;
  if (i >= PART_STRIDE) return;
  float a0 = 0.f, a1 = 0.f, a2 = 0.f, a3 = 0.f;
  int p = 0;
  for (; p + 3 < P; p += 4) {
    a0 += part[(size_t)(p + 0) * PART_STRIDE + i];
    a1 += part[(size_t)(p + 1) * PART_STRIDE + i];
    a2 += part[(size_t)(p + 2) * PART_STRIDE + i];
    a3 += part[(size_t)(p + 3) * PART_STRIDE + i];
  }
  for (; p < P; ++p) a0 += part[(size_t)p * PART_STRIDE + i];
  ws[WS_NI + i] = (a0 + a1) + (a2 + a3);
}

// EMA update + losses. One block, 512 threads (one per code).
__global__ __launch_bounds__(512) void vq_final(const float* __restrict__ Nin,
                                                const float* __restrict__ Min,
                                                const float* __restrict__ ws,
                                                float* __restrict__ out) {
  __shared__ float red[512];
  int c = threadIdx.x;
  float niv = ws[WS_NI + c];
  float Nn = Nin[c] * DECAYF + OMDECAY * niv;
  out[OFF_NNEW + c] = Nn;
  red[c] = Nn;
  __syncthreads();
#pragma unroll
  for (int s = 256; s > 0; s >>= 1) {
    if (c < s) red[c] += red[c + s];
    __syncthreads();
  }
  float n = red[0];
  float Nsm = (Nn + EPSF) / (n + (float)CODES * EPSF) * n;
  for (int d = 0; d < DIM; ++d) {
    float m = Min[d * CODES + c] * DECAYF + OMDECAY * ws[WS_EOFX + d * CODES + c];
    out[OFF_MNEW + d * CODES + c] = m;
    out[OFF_ENEW + d * CODES + c] = m / Nsm;
  }
  if (c == 0) {
    float l = ws[WS_LOSS] / (float)XELEMS;
    out[OFF_QL] = l;
    out[OFF_CL] = l;
  }
}

extern "C" void kernel_launch(void* const* d_in, const int* in_sizes, int n_in,
                              void* d_out, int out_size, void* d_ws, size_t ws_size,
                              hipStream_t stream) {
  const float* x = (const float*)d_in[0];
  const float* emb = (const float*)d_in[1];
  const float* Nin = (const float*)d_in[2];
  const float* Min = (const float*)d_in[3];
  float* out = (float*)d_out;
  float* ws = (float*)d_ws;
  int* idxw = (int*)(ws + WS_IDX);

  // pick P (power of two, <=256) that fits partials in ws
  size_t avail = ws_size / 4;
  int P = 0;
  if (avail > (size_t)WS_PART) {
    size_t cap = (avail - WS_PART) / PART_STRIDE;
    P = 256;
    while (P > (int)cap) P >>= 1;
    if (P < 64) P = 0;  // too few partials -> atomic-flush fallback
  }

  // zero accumulator region [cnorm..loss]; eT fully overwritten by vq_prep
  hipMemsetAsync(d_ws, 0, (size_t)WS_ET * sizeof(float), stream);

  vq_prep<<<1, 512, 0, stream>>>(emb, ws);

  vq_main<<<TOKENS / 256, 256, 0, stream>>>(
      x, ws + WS_CNORM, ws + WS_ET, ws + WS_LOSS,
      out + OFF_Q, out + OFF_IDX, idxw);

  if (P > 0) {
    vq_segsum<<<P, 256, 0, stream>>>(x, idxw, ws + WS_PART, TOKENS / P,
                                     PART_STRIDE, 0);
    vq_reduce<<<(PART_STRIDE + 255) / 256, 256, 0, stream>>>(ws + WS_PART, ws, P);
  } else {
    vq_segsum<<<256, 256, 0, stream>>>(x, idxw, ws + WS_NI, TOKENS / 256, 0, 1);
  }

  vq_final<<<1, 512, 0, stream>>>(Nin, Min, ws, out);
}

// Round 3
// 586.045 us; speedup vs baseline: 1.8203x; 1.1752x over previous
//
#include <hip/hip_runtime.h>
#include <hip/hip_bf16.h>
#include <math.h>

#define DIM 64
#define CODES 512
#define TOKENS 262144
#define XELEMS 16777216

#define DECAYF 0.99f
#define OMDECAY 0.01f
#define EPSF 1e-5f
#define MARGIN 3.0f

// workspace float offsets
#define WS_CNORM 0            // 512
#define WS_NI    512          // 512
#define WS_EOFX  1024         // 64*512
#define WS_LOSS  33792        // 1 (+pad)
#define WS_ET    33800        // 512*64 fp32 eT
#define WS_EBF   66568        // 512*72 ushort bf16 eT (padded rows) = 18432 floats
#define WS_IDX   85000        // 262144 int32
#define WS_PART  347144       // P partials of PART_STRIDE
#define PART_STRIDE 33280

// output float offsets
#define OFF_Q    0
#define OFF_QL   16777216
#define OFF_IDX  16777217
#define OFF_CL   17039361
#define OFF_ENEW 17039362
#define OFF_NNEW 17072130
#define OFF_MNEW 17072642

typedef __attribute__((ext_vector_type(8))) short bf16x8;
typedef __attribute__((ext_vector_type(4))) float f32x4;

static __device__ inline short f2bf(float f) {
  __hip_bfloat16 h = __float2bfloat16(f);
  return *reinterpret_cast<short*>(&h);
}

// Exact fp32 distance, same accumulation structure as the R2 kernel (passed).
static __device__ inline float exact_dist(const float* __restrict__ x,
                                          const float* __restrict__ eT,
                                          const float* cn, int t, int c) {
  const float* xr = x + (size_t)t * DIM;
  const float* er = eT + (size_t)c * DIM;
  float d0 = 0.f, d1 = 0.f, d2 = 0.f, d3 = 0.f;
  float s0 = 0.f, s1 = 0.f, s2 = 0.f, s3 = 0.f;
#pragma unroll
  for (int d = 0; d < DIM; d += 4) {
    float x0 = xr[d], x1 = xr[d + 1], x2 = xr[d + 2], x3 = xr[d + 3];
    d0 = fmaf(x0, er[d], d0);
    d1 = fmaf(x1, er[d + 1], d1);
    d2 = fmaf(x2, er[d + 2], d2);
    d3 = fmaf(x3, er[d + 3], d3);
    s0 = fmaf(x0, x0, s0);
    s1 = fmaf(x1, x1, s1);
    s2 = fmaf(x2, x2, s2);
    s3 = fmaf(x3, x3, s3);
  }
  float dot = (d0 + d1) + (d2 + d3);
  float sx = (s0 + s1) + (s2 + s3);
  return (sx - 2.0f * dot) + cn[c];
}

// Prep: eT fp32 [512][64], ebf bf16 padded [512][72], cnorm fp32.
__global__ __launch_bounds__(512) void vq_prep(const float* __restrict__ emb,
                                               float* __restrict__ ws) {
  int c = threadIdx.x;
  float* eT = ws + WS_ET;
  unsigned short* ebf = (unsigned short*)(ws + WS_EBF);
  float a0 = 0.f, a1 = 0.f, a2 = 0.f, a3 = 0.f;
#pragma unroll
  for (int d = 0; d < DIM; d += 4) {
    float v0 = emb[(d + 0) * CODES + c];
    float v1 = emb[(d + 1) * CODES + c];
    float v2 = emb[(d + 2) * CODES + c];
    float v3 = emb[(d + 3) * CODES + c];
    eT[c * DIM + d + 0] = v0;
    eT[c * DIM + d + 1] = v1;
    eT[c * DIM + d + 2] = v2;
    eT[c * DIM + d + 3] = v3;
    ebf[c * 72 + d + 0] = (unsigned short)f2bf(v0);
    ebf[c * 72 + d + 1] = (unsigned short)f2bf(v1);
    ebf[c * 72 + d + 2] = (unsigned short)f2bf(v2);
    ebf[c * 72 + d + 3] = (unsigned short)f2bf(v3);
    a0 = fmaf(v0, v0, a0);
    a1 = fmaf(v1, v1, a1);
    a2 = fmaf(v2, v2, a2);
    a3 = fmaf(v3, v3, a3);
  }
#pragma unroll
  for (int d = DIM; d < 72; ++d) ebf[c * 72 + d] = 0;
  ws[WS_CNORM + c] = (a0 + a1) + (a2 + a3);
}

// MFMA screening + exact rescue. Block = 4 waves, wave = 16 tokens x 512 codes.
__global__ __launch_bounds__(256, 2) void vq_main_mfma(
    const float* __restrict__ x, const float* __restrict__ ws,
    float* __restrict__ loss_sum, float* __restrict__ q_out,
    float* __restrict__ idx_out, int* __restrict__ idx_int) {
  __shared__ __align__(16) unsigned short ebf[CODES * 72];  // 73728 B
  __shared__ float cn[CODES];

  const float* eT = ws + WS_ET;

  // stage ebf (linear copy, pads included) + cnorm
  {
    const float4* src = (const float4*)(ws + WS_EBF);
    float4* dst = (float4*)ebf;
    for (int i = threadIdx.x; i < (CODES * 72 * 2) / 16; i += 256) dst[i] = src[i];
    for (int i = threadIdx.x; i < CODES; i += 256) cn[i] = ws[WS_CNORM + i];
  }
  __syncthreads();

  const int lane = threadIdx.x & 63;
  const int wave = threadIdx.x >> 6;
  const int n = lane & 15;
  const int quad = lane >> 4;
  const int t0 = blockIdx.x * 64 + wave * 16;

  // A-frags: bf16(-2x). A[m=lane&15][k=quad*8+j]; two k-halves.
  bf16x8 a0, a1;
  {
    const float* xr = x + (size_t)(t0 + n) * DIM + quad * 8;
    float4 v0 = *(const float4*)(xr);
    float4 v1 = *(const float4*)(xr + 4);
    float4 v2 = *(const float4*)(xr + 32);
    float4 v3 = *(const float4*)(xr + 36);
    a0[0] = f2bf(-2.f * v0.x); a0[1] = f2bf(-2.f * v0.y);
    a0[2] = f2bf(-2.f * v0.z); a0[3] = f2bf(-2.f * v0.w);
    a0[4] = f2bf(-2.f * v1.x); a0[5] = f2bf(-2.f * v1.y);
    a0[6] = f2bf(-2.f * v1.z); a0[7] = f2bf(-2.f * v1.w);
    a1[0] = f2bf(-2.f * v2.x); a1[1] = f2bf(-2.f * v2.y);
    a1[2] = f2bf(-2.f * v2.z); a1[3] = f2bf(-2.f * v2.w);
    a1[4] = f2bf(-2.f * v3.x); a1[5] = f2bf(-2.f * v3.y);
    a1[6] = f2bf(-2.f * v3.z); a1[7] = f2bf(-2.f * v3.w);
  }

  const unsigned short* brow = ebf + n * 72 + quad * 8;

  // Pass 1: screened min per token (rows quad*4+r, col n).
  float best[4] = {1e30f, 1e30f, 1e30f, 1e30f};
  for (int cc = 0; cc < 32; ++cc) {
    const unsigned short* bp = brow + cc * 16 * 72;
    bf16x8 b0 = *(const bf16x8*)(bp);
    bf16x8 b1 = *(const bf16x8*)(bp + 32);
    f32x4 acc = {0.f, 0.f, 0.f, 0.f};
    acc = __builtin_amdgcn_mfma_f32_16x16x32_bf16(a0, b0, acc, 0, 0, 0);
    acc = __builtin_amdgcn_mfma_f32_16x16x32_bf16(a1, b1, acc, 0, 0, 0);
    float c_n = cn[cc * 16 + n];
#pragma unroll
    for (int r = 0; r < 4; ++r) best[r] = fminf(best[r], acc[r] + c_n);
  }
  float minr[4];
#pragma unroll
  for (int r = 0; r < 4; ++r) {
    float m = best[r];
    m = fminf(m, __shfl_xor(m, 1, 16));
    m = fminf(m, __shfl_xor(m, 2, 16));
    m = fminf(m, __shfl_xor(m, 4, 16));
    m = fminf(m, __shfl_xor(m, 8, 16));
    minr[r] = m;
  }

  // Pass 2: identical replay; collect candidates within margin (5 slots in u64).
  unsigned long long clist = 0ull;
  int nc = 0;
  for (int cc = 0; cc < 32; ++cc) {
    const unsigned short* bp = brow + cc * 16 * 72;
    bf16x8 b0 = *(const bf16x8*)(bp);
    bf16x8 b1 = *(const bf16x8*)(bp + 32);
    f32x4 acc = {0.f, 0.f, 0.f, 0.f};
    acc = __builtin_amdgcn_mfma_f32_16x16x32_bf16(a0, b0, acc, 0, 0, 0);
    acc = __builtin_amdgcn_mfma_f32_16x16x32_bf16(a1, b1, acc, 0, 0, 0);
    float c_n = cn[cc * 16 + n];
#pragma unroll
    for (int r = 0; r < 4; ++r) {
      float dscr = acc[r] + c_n;
      if (dscr <= minr[r] + MARGIN) {
        if (nc < 5)
          clist |= (unsigned long long)((((cc * 16 + n) << 2) | r) & 0x7FF)
                   << (11 * nc);
        ++nc;
      }
    }
  }

  // Exact fp32 rescue of candidates; lowest-index tie-break.
  float bval[4] = {1e30f, 1e30f, 1e30f, 1e30f};
  int bidx[4] = {1 << 20, 1 << 20, 1 << 20, 1 << 20};
  if (nc > 5) {  // overflow fallback (~never): exact scan of this lane's codes
    for (int cc = 0; cc < 32; ++cc) {
      int c = cc * 16 + n;
#pragma unroll
      for (int r = 0; r < 4; ++r) {
        float dv = exact_dist(x, eT, cn, t0 + quad * 4 + r, c);
        if (dv < bval[r] || (dv == bval[r] && c < bidx[r])) {
          bval[r] = dv;
          bidx[r] = c;
        }
      }
    }
  } else {
    for (int i = 0; i < nc; ++i) {
      int pk = (int)((clist >> (11 * i)) & 0x7FF);
      int c = pk >> 2;
      int r = pk & 3;
      float dv = exact_dist(x, eT, cn, t0 + quad * 4 + (r & 3), c);
#pragma unroll
      for (int rr = 0; rr < 4; ++rr) {
        if (rr == r) {
          if (dv < bval[rr] || (dv == bval[rr] && c < bidx[rr])) {
            bval[rr] = dv;
            bidx[rr] = c;
          }
        }
      }
    }
  }

  // Cross-lane lexicographic (val, idx) min within each quad's 16 lanes.
  int win[4];
#pragma unroll
  for (int r = 0; r < 4; ++r) {
    float v = bval[r];
    int ix = bidx[r];
#pragma unroll
    for (int mask = 1; mask <= 8; mask <<= 1) {
      float ov = __shfl_xor(v, mask, 16);
      int oi = __shfl_xor(ix, mask, 16);
      if (ov < v || (ov == v && oi < ix)) {
        v = ov;
        ix = oi;
      }
    }
    win[r] = ix;
  }

  // Epilogue: 16 lanes per quad cooperatively write each token's q row + loss.
  float lsum = 0.f;
#pragma unroll
  for (int r = 0; r < 4; ++r) {
    int t = t0 + quad * 4 + r;
    int w = win[r];
    float4 e4 = *(const float4*)(eT + (size_t)w * DIM + n * 4);
    float4 x4 = *(const float4*)(x + (size_t)t * DIM + n * 4);
    *(float4*)(q_out + (size_t)t * DIM + n * 4) = e4;
    float u0 = x4.x - e4.x, u1 = x4.y - e4.y;
    float u2 = x4.z - e4.z, u3 = x4.w - e4.w;
    lsum = fmaf(u0, u0, lsum);
    lsum = fmaf(u1, u1, lsum);
    lsum = fmaf(u2, u2, lsum);
    lsum = fmaf(u3, u3, lsum);
    if (n == 0) {
      idx_out[t] = (float)w;
      idx_int[t] = w;
    }
  }
#pragma unroll
  for (int off = 32; off > 0; off >>= 1) lsum += __shfl_down(lsum, off, 64);
  if (lane == 0) atomicAdd(loss_sum, lsum);
}

// Segment sum with LDS privatization (unchanged from R2).
__global__ __launch_bounds__(256) void vq_segsum(
    const float* __restrict__ x,
    const int* __restrict__ idx,
    float* __restrict__ dest_base,
    int tokens_per_block,
    int part_stride,
    int aflush) {
  __shared__ float lds_n[CODES];
  __shared__ float lds_e[DIM * 128];
  int p = blockIdx.x;
  int t0 = p * tokens_per_block;
  float* dest = dest_base + (size_t)p * part_stride;

  for (int i = threadIdx.x; i < CODES; i += 256) lds_n[i] = 0.f;

  for (int q = 0; q < 4; ++q) {
    for (int i = threadIdx.x; i < DIM * 128; i += 256) lds_e[i] = 0.f;
    __syncthreads();

    for (int tt = threadIdx.x; tt < tokens_per_block; tt += 256) {
      int t = t0 + tt;
      int bi = idx[t];
      if (q == 0) atomicAdd(&lds_n[bi], 1.0f);
      int cl = bi - q * 128;
      if (cl >= 0 && cl < 128) {
        const float4* xp = (const float4*)(x + (size_t)t * DIM);
#pragma unroll
        for (int i = 0; i < DIM / 4; ++i) {
          float4 v = xp[i];
          atomicAdd(&lds_e[(4 * i + 0) * 128 + cl], v.x);
          atomicAdd(&lds_e[(4 * i + 1) * 128 + cl], v.y);
          atomicAdd(&lds_e[(4 * i + 2) * 128 + cl], v.z);
          atomicAdd(&lds_e[(4 * i + 3) * 128 + cl], v.w);
        }
      }
    }
    __syncthreads();

    for (int i = threadIdx.x; i < DIM * 128; i += 256) {
      int d = i >> 7, cl = i & 127;
      float v = lds_e[i];
      int o = CODES + d * CODES + q * 128 + cl;
      if (aflush) {
        if (v != 0.f) atomicAdd(&dest[o], v);
      } else {
        dest[o] = v;
      }
    }
    __syncthreads();
  }

  for (int i = threadIdx.x; i < CODES; i += 256) {
    float v = lds_n[i];
    if (aflush) {
      if (v != 0.f) atomicAdd(&dest[i], v);
    } else {
      dest[i] = v;
    }
  }
}

__global__ __launch_bounds__(256) void vq_reduce(const float* __restrict__ part,
                                                 float* __restrict__ ws,
                                                 int P) {
  int i = blockIdx.x * 256 + threadIdx.x;
  if (i >= PART_STRIDE) return;
  float a0 = 0.f, a1 = 0.f, a2 = 0.f, a3 = 0.f;
  int p = 0;
  for (; p + 3 < P; p += 4) {
    a0 += part[(size_t)(p + 0) * PART_STRIDE + i];
    a1 += part[(size_t)(p + 1) * PART_STRIDE + i];
    a2 += part[(size_t)(p + 2) * PART_STRIDE + i];
    a3 += part[(size_t)(p + 3) * PART_STRIDE + i];
  }
  for (; p < P; ++p) a0 += part[(size_t)p * PART_STRIDE + i];
  ws[WS_NI + i] = (a0 + a1) + (a2 + a3);
}

// EMA update + losses. Grid = DIM blocks (one per d), 512 threads (one per code).
__global__ __launch_bounds__(512) void vq_final(const float* __restrict__ Nin,
                                                const float* __restrict__ Min,
                                                const float* __restrict__ ws,
                                                float* __restrict__ out) {
  __shared__ float red[512];
  int c = threadIdx.x;
  int d = blockIdx.x;
  float niv = ws[WS_NI + c];
  float Nn = Nin[c] * DECAYF + OMDECAY * niv;
  red[c] = Nn;
  __syncthreads();
#pragma unroll
  for (int s = 256; s > 0; s >>= 1) {
    if (c < s) red[c] += red[c + s];
    __syncthreads();
  }
  float n = red[0];
  float Nsm = (Nn + EPSF) / (n + (float)CODES * EPSF) * n;
  float m = Min[d * CODES + c] * DECAYF + OMDECAY * ws[WS_EOFX + d * CODES + c];
  out[OFF_MNEW + d * CODES + c] = m;
  out[OFF_ENEW + d * CODES + c] = m / Nsm;
  if (d == 0) {
    out[OFF_NNEW + c] = Nn;
    if (c == 0) {
      float l = ws[WS_LOSS] / (float)XELEMS;
      out[OFF_QL] = l;
      out[OFF_CL] = l;
    }
  }
}

extern "C" void kernel_launch(void* const* d_in, const int* in_sizes, int n_in,
                              void* d_out, int out_size, void* d_ws, size_t ws_size,
                              hipStream_t stream) {
  const float* x = (const float*)d_in[0];
  const float* emb = (const float*)d_in[1];
  const float* Nin = (const float*)d_in[2];
  const float* Min = (const float*)d_in[3];
  float* out = (float*)d_out;
  float* ws = (float*)d_ws;
  int* idxw = (int*)(ws + WS_IDX);

  size_t avail = ws_size / 4;
  int P = 0;
  if (avail > (size_t)WS_PART) {
    size_t cap = (avail - WS_PART) / PART_STRIDE;
    P = 256;
    while (P > (int)cap) P >>= 1;
    if (P < 64) P = 0;
  }

  // zero accumulator region [cnorm..loss]
  hipMemsetAsync(d_ws, 0, (size_t)WS_ET * sizeof(float), stream);

  vq_prep<<<1, 512, 0, stream>>>(emb, ws);

  vq_main_mfma<<<TOKENS / 64, 256, 0, stream>>>(
      x, ws, ws + WS_LOSS, out + OFF_Q, out + OFF_IDX, idxw);

  if (P > 0) {
    vq_segsum<<<P, 256, 0, stream>>>(x, idxw, ws + WS_PART, TOKENS / P,
                                     PART_STRIDE, 0);
    vq_reduce<<<(PART_STRIDE + 255) / 256, 256, 0, stream>>>(ws + WS_PART, ws, P);
  } else {
    vq_segsum<<<256, 256, 0, stream>>>(x, idxw, ws + WS_NI, TOKENS / 256, 0, 1);
  }

  vq_final<<<DIM, 512, 0, stream>>>(Nin, Min, ws, out);
}

// Round 4
// 434.568 us; speedup vs baseline: 2.4547x; 1.3486x over previous
//
#include <hip/hip_runtime.h>
#include <hip/hip_bf16.h>
#include <math.h>

#define DIM 64
#define CODES 512
#define HALFC 256
#define TOKENS 262144
#define XELEMS 16777216

#define DECAYF 0.99f
#define OMDECAY 0.01f
#define EPSF 1e-5f

// workspace float offsets
#define WS_CNORM 0            // 512
#define WS_NI    512          // 512
#define WS_EOFX  1024         // 32768
#define WS_LOSS  33792        // 16
#define WS_ET    33808        // 32768 fp32 eT [512][64]
#define WS_IMG   66576        // 32768 floats = 128 KB bf16 hi/lo B-fragment image
#define WS_CV    99344        // 2*262144 float2 = 1048576 floats
#define WS_CI    1147920      // 2*262144 int2   = 1048576 floats
#define WS_IDX   2196496      // 262144 int32
#define WS_PART  2458640      // P * PART_STRIDE
#define PART_STRIDE 33280

// output float offsets (reference return order)
#define OFF_Q    0
#define OFF_QL   16777216
#define OFF_IDX  16777217
#define OFF_CL   17039361
#define OFF_ENEW 17039362
#define OFF_NNEW 17072130
#define OFF_MNEW 17072642

typedef __attribute__((ext_vector_type(8))) short bf16x8;
typedef __attribute__((ext_vector_type(4))) float f32x4;

static __device__ inline short f2bf(float f) {
  __hip_bfloat16 h = __float2bfloat16(f);
  return *reinterpret_cast<short*>(&h);
}
static __device__ inline float bf2f(short s) {
  unsigned int u = ((unsigned int)(unsigned short)s) << 16;
  return __uint_as_float(u);
}

// Prep: thread per code. eT fp32 rows, cnorm (deterministic order), and the
// B-fragment image: [half][cc][khalf][hi/lo][lane*8+j] shorts, so screen's
// ds_read_b128 at lane*16B is conflict-free.
__global__ __launch_bounds__(256) void vq_prep(const float* __restrict__ emb,
                                               float* __restrict__ ws) {
  int c = blockIdx.x * 256 + threadIdx.x;  // 0..511
  unsigned short* img = (unsigned short*)(ws + WS_IMG);
  float* eT = ws + WS_ET;
  int hbase = (c >> 8) * (16 * 2048);  // shorts
  int ch = c & 255;
  int cc = ch >> 4;
  int n = ch & 15;
  float cn = 0.f;
#pragma unroll
  for (int d0 = 0; d0 < DIM; d0 += 4) {
    float v[4];
#pragma unroll
    for (int u = 0; u < 4; ++u) {
      v[u] = emb[(d0 + u) * CODES + c];
      cn = fmaf(v[u], v[u], cn);
    }
    *(float4*)(eT + (size_t)c * DIM + d0) = make_float4(v[0], v[1], v[2], v[3]);
    int kh = d0 >> 5, kk = d0 & 31, qd = kk >> 3, j0 = kk & 7;
    int lane = qd * 16 + n;
    unsigned short hi[4], lo[4];
#pragma unroll
    for (int u = 0; u < 4; ++u) {
      hi[u] = (unsigned short)f2bf(v[u]);
      lo[u] = (unsigned short)f2bf(v[u] - bf2f((short)hi[u]));
    }
    int base = hbase + cc * 2048 + kh * 1024 + lane * 8 + j0;
    *(ushort4*)(img + base) = make_ushort4(hi[0], hi[1], hi[2], hi[3]);
    *(ushort4*)(img + base + 512) = make_ushort4(lo[0], lo[1], lo[2], lo[3]);
  }
  ws[WS_CNORM + c] = cn;
}

// Screen: compensated bf16 MFMA top-2 per token over one code-half.
// Block = 4 waves x 64 tokens; half = blockIdx&1. LDS: 64KB B-frags + cn.
__global__ __launch_bounds__(256, 2) void vq_screen(
    const float* __restrict__ x, const float* __restrict__ ws,
    float2* __restrict__ cv, int2* __restrict__ ci) {
  __shared__ __align__(16) unsigned short bimg[32768];  // 64 KB
  __shared__ float cn_l[HALFC];
  const int h = blockIdx.x & 1;
  const int tg = blockIdx.x >> 1;

  {
    const float4* src = (const float4*)(ws + WS_IMG + h * 16384);
    float4* dst = (float4*)bimg;
    for (int i = threadIdx.x; i < 4096; i += 256) dst[i] = src[i];
    for (int i = threadIdx.x; i < HALFC; i += 256)
      cn_l[i] = ws[WS_CNORM + h * HALFC + i];
  }
  __syncthreads();

  const int lane = threadIdx.x & 63;
  const int wave = threadIdx.x >> 6;
  const int n = lane & 15;
  const int quad = lane >> 4;
  const int t0 = tg * 256 + wave * 64;

  // A-fragments hi/lo of -2x for 4 token tiles, kept in regs for the whole loop
  bf16x8 ah[4][2], al[4][2];
#pragma unroll
  for (int tile = 0; tile < 4; ++tile) {
    const float* xr = x + (size_t)(t0 + tile * 16 + n) * DIM + quad * 8;
#pragma unroll
    for (int kh = 0; kh < 2; ++kh) {
      float4 v0 = *(const float4*)(xr + kh * 32);
      float4 v1 = *(const float4*)(xr + kh * 32 + 4);
      float f[8] = {v0.x, v0.y, v0.z, v0.w, v1.x, v1.y, v1.z, v1.w};
#pragma unroll
      for (int j = 0; j < 8; ++j) {
        float m2 = -2.f * f[j];
        short hi = f2bf(m2);
        ah[tile][kh][j] = hi;
        al[tile][kh][j] = f2bf(m2 - bf2f(hi));
      }
    }
  }

  float v1[4][4], v2[4][4];
  int i1[4][4], i2[4][4];
#pragma unroll
  for (int tile = 0; tile < 4; ++tile)
#pragma unroll
    for (int r = 0; r < 4; ++r) {
      v1[tile][r] = 1e30f;
      v2[tile][r] = 1e30f;
      i1[tile][r] = 0x3FFFFFFF;
      i2[tile][r] = 0x3FFFFFFF;
    }

  for (int cc = 0; cc < 16; ++cc) {
    const unsigned short* bp = bimg + cc * 2048;
    bf16x8 bh0 = *(const bf16x8*)(bp + lane * 8);
    bf16x8 bl0 = *(const bf16x8*)(bp + 512 + lane * 8);
    bf16x8 bh1 = *(const bf16x8*)(bp + 1024 + lane * 8);
    bf16x8 bl1 = *(const bf16x8*)(bp + 1536 + lane * 8);
    float cnv = cn_l[cc * 16 + n];
    int cid = h * HALFC + cc * 16 + n;
#pragma unroll
    for (int tile = 0; tile < 4; ++tile) {
      f32x4 acc = {0.f, 0.f, 0.f, 0.f};
      acc = __builtin_amdgcn_mfma_f32_16x16x32_bf16(ah[tile][0], bh0, acc, 0, 0, 0);
      acc = __builtin_amdgcn_mfma_f32_16x16x32_bf16(al[tile][0], bh0, acc, 0, 0, 0);
      acc = __builtin_amdgcn_mfma_f32_16x16x32_bf16(ah[tile][0], bl0, acc, 0, 0, 0);
      acc = __builtin_amdgcn_mfma_f32_16x16x32_bf16(ah[tile][1], bh1, acc, 0, 0, 0);
      acc = __builtin_amdgcn_mfma_f32_16x16x32_bf16(al[tile][1], bh1, acc, 0, 0, 0);
      acc = __builtin_amdgcn_mfma_f32_16x16x32_bf16(ah[tile][1], bl1, acc, 0, 0, 0);
#pragma unroll
      for (int r = 0; r < 4; ++r) {
        float s = acc[r] + cnv;
        bool c1 = s < v1[tile][r];
        bool c2 = s < v2[tile][r];
        i2[tile][r] = c1 ? i1[tile][r] : (c2 ? cid : i2[tile][r]);
        v2[tile][r] = fminf(fmaxf(s, v1[tile][r]), v2[tile][r]);  // med3
        i1[tile][r] = c1 ? cid : i1[tile][r];
        v1[tile][r] = fminf(s, v1[tile][r]);
      }
    }
  }

  // butterfly top-2 merge across the quad's 16 lanes
#pragma unroll
  for (int m = 1; m < 16; m <<= 1) {
#pragma unroll
    for (int tile = 0; tile < 4; ++tile)
#pragma unroll
      for (int r = 0; r < 4; ++r) {
        float ov1 = __shfl_xor(v1[tile][r], m, 16);
        int oi1 = __shfl_xor(i1[tile][r], m, 16);
        float ov2 = __shfl_xor(v2[tile][r], m, 16);
        int oi2 = __shfl_xor(i2[tile][r], m, 16);
        bool f = ov1 < v1[tile][r];
        float hi = f ? v1[tile][r] : ov1;
        int hii = f ? i1[tile][r] : oi1;
        v1[tile][r] = f ? ov1 : v1[tile][r];
        i1[tile][r] = f ? oi1 : i1[tile][r];
        bool g = ov2 < v2[tile][r];
        float lo2 = g ? ov2 : v2[tile][r];
        int lo2i = g ? oi2 : i2[tile][r];
        bool e2 = hi < lo2;
        v2[tile][r] = e2 ? hi : lo2;
        i2[tile][r] = e2 ? hii : lo2i;
      }
  }

  if (n == 0) {
#pragma unroll
    for (int tile = 0; tile < 4; ++tile)
#pragma unroll
      for (int r = 0; r < 4; ++r) {
        int t = t0 + tile * 16 + quad * 4 + r;
        cv[(size_t)h * TOKENS + t] = make_float2(v1[tile][r], v2[tile][r]);
        ci[(size_t)h * TOKENS + t] = make_int2(i1[tile][r], i2[tile][r]);
      }
  }
}

// Resolve: merge half top-2s, exact fp32 compare (16 lanes/token, coalesced),
// write q/idx, accumulate loss. Fused epilogue == free "rescue".
__global__ __launch_bounds__(256) void vq_resolve(
    const float* __restrict__ x, const float* __restrict__ ws,
    const float2* __restrict__ cv, const int2* __restrict__ ci,
    float* __restrict__ loss_sum, float* __restrict__ q_out,
    float* __restrict__ idx_out, int* __restrict__ idx_int) {
  const float* eT = ws + WS_ET;
  const float* cn = ws + WS_CNORM;
  const int lane = threadIdx.x & 63;
  const int wave = threadIdx.x >> 6;
  const int n = lane & 15;
  const int quad = lane >> 4;
  const int tb = blockIdx.x * 256 + wave * 64;

  float loss = 0.f;
  for (int it = 0; it < 16; ++it) {
    int t = tb + it * 4 + quad;
    float2 va = cv[t];
    int2 ia = ci[t];
    float2 vb = cv[(size_t)TOKENS + t];
    int2 ib = ci[(size_t)TOKENS + t];
    int c1, c2;
    if (vb.x < va.x) {
      c1 = ib.x;
      c2 = (va.x < vb.y) ? ia.x : ib.y;
    } else {
      c1 = ia.x;
      c2 = (vb.x < va.y) ? ib.x : ia.y;
    }
    float4 xv = *(const float4*)(x + (size_t)t * DIM + n * 4);
    float4 e1 = *(const float4*)(eT + (size_t)c1 * DIM + n * 4);
    float4 e2 = *(const float4*)(eT + (size_t)c2 * DIM + n * 4);
    float p1 = xv.x * e1.x;
    p1 = fmaf(xv.y, e1.y, p1);
    p1 = fmaf(xv.z, e1.z, p1);
    p1 = fmaf(xv.w, e1.w, p1);
    float p2 = xv.x * e2.x;
    p2 = fmaf(xv.y, e2.y, p2);
    p2 = fmaf(xv.z, e2.z, p2);
    p2 = fmaf(xv.w, e2.w, p2);
#pragma unroll
    for (int m = 1; m < 16; m <<= 1) {
      p1 += __shfl_xor(p1, m, 16);
      p2 += __shfl_xor(p2, m, 16);
    }
    float d1 = fmaf(-2.f, p1, cn[c1]);
    float d2 = fmaf(-2.f, p2, cn[c2]);
    bool take2 = (d2 < d1) || (d2 == d1 && c2 < c1);
    int w = take2 ? c2 : c1;
    float4 q = take2 ? e2 : e1;
    *(float4*)(q_out + (size_t)t * DIM + n * 4) = q;
    float u0 = xv.x - q.x, u1 = xv.y - q.y, u2 = xv.z - q.z, u3 = xv.w - q.w;
    loss = fmaf(u0, u0, loss);
    loss = fmaf(u1, u1, loss);
    loss = fmaf(u2, u2, loss);
    loss = fmaf(u3, u3, loss);
    if (n == 0) {
      idx_out[t] = (float)w;
      idx_int[t] = w;
    }
  }
#pragma unroll
  for (int off = 32; off > 0; off >>= 1) loss += __shfl_down(loss, off, 64);
  if (lane == 0) atomicAdd(loss_sum, loss);
}

// Segment sum, LDS privatized, 2 half-passes of 256 codes (64KB tile).
__global__ __launch_bounds__(256) void vq_segsum(
    const float* __restrict__ x, const int* __restrict__ idx,
    float* __restrict__ dest_base, int tokens_per_block, int part_stride,
    int aflush) {
  __shared__ float lds_n[CODES];
  __shared__ float lds_e[DIM * 256];
  int p = blockIdx.x;
  int t0 = p * tokens_per_block;
  float* dest = dest_base + (size_t)p * part_stride;

  for (int i = threadIdx.x; i < CODES; i += 256) lds_n[i] = 0.f;

  for (int q = 0; q < 2; ++q) {
    for (int i = threadIdx.x; i < DIM * 256; i += 256) lds_e[i] = 0.f;
    __syncthreads();

    for (int tt = threadIdx.x; tt < tokens_per_block; tt += 256) {
      int t = t0 + tt;
      int bi = idx[t];
      if (q == 0) atomicAdd(&lds_n[bi], 1.0f);
      int cl = bi - q * 256;
      if (cl >= 0 && cl < 256) {
        const float4* xp = (const float4*)(x + (size_t)t * DIM);
#pragma unroll
        for (int i = 0; i < DIM / 4; ++i) {
          float4 v = xp[i];
          atomicAdd(&lds_e[(4 * i + 0) * 256 + cl], v.x);
          atomicAdd(&lds_e[(4 * i + 1) * 256 + cl], v.y);
          atomicAdd(&lds_e[(4 * i + 2) * 256 + cl], v.z);
          atomicAdd(&lds_e[(4 * i + 3) * 256 + cl], v.w);
        }
      }
    }
    __syncthreads();

    for (int i = threadIdx.x; i < DIM * 256; i += 256) {
      int d = i >> 8, cl = i & 255;
      float v = lds_e[i];
      int o = CODES + d * CODES + q * 256 + cl;
      if (aflush) {
        if (v != 0.f) atomicAdd(&dest[o], v);
      } else {
        dest[o] = v;
      }
    }
    __syncthreads();
  }

  for (int i = threadIdx.x; i < CODES; i += 256) {
    float v = lds_n[i];
    if (aflush) {
      if (v != 0.f) atomicAdd(&dest[i], v);
    } else {
      dest[i] = v;
    }
  }
}

__global__ __launch_bounds__(256) void vq_reduce(const float* __restrict__ part,
                                                 float* __restrict__ ws, int P) {
  int i = blockIdx.x * 256 + threadIdx.x;
  if (i >= PART_STRIDE) return;
  float a0 = 0.f, a1 = 0.f, a2 = 0.f, a3 = 0.f;
  int p = 0;
  for (; p + 3 < P; p += 4) {
    a0 += part[(size_t)(p + 0) * PART_STRIDE + i];
    a1 += part[(size_t)(p + 1) * PART_STRIDE + i];
    a2 += part[(size_t)(p + 2) * PART_STRIDE + i];
    a3 += part[(size_t)(p + 3) * PART_STRIDE + i];
  }
  for (; p < P; ++p) a0 += part[(size_t)p * PART_STRIDE + i];
  ws[WS_NI + i] = (a0 + a1) + (a2 + a3);
}

// EMA update + losses. Grid = DIM blocks, one thread per code.
__global__ __launch_bounds__(512) void vq_final(const float* __restrict__ Nin,
                                                const float* __restrict__ Min,
                                                const float* __restrict__ ws,
                                                float* __restrict__ out) {
  __shared__ float red[512];
  int c = threadIdx.x;
  int d = blockIdx.x;
  float niv = ws[WS_NI + c];
  float Nn = Nin[c] * DECAYF + OMDECAY * niv;
  red[c] = Nn;
  __syncthreads();
#pragma unroll
  for (int s = 256; s > 0; s >>= 1) {
    if (c < s) red[c] += red[c + s];
    __syncthreads();
  }
  float nsum = red[0];
  float Nsm = (Nn + EPSF) / (nsum + (float)CODES * EPSF) * nsum;
  float m = Min[d * CODES + c] * DECAYF + OMDECAY * ws[WS_EOFX + d * CODES + c];
  out[OFF_MNEW + d * CODES + c] = m;
  out[OFF_ENEW + d * CODES + c] = m / Nsm;
  if (d == 0) {
    out[OFF_NNEW + c] = Nn;
    if (c == 0) {
      float l = ws[WS_LOSS] / (float)XELEMS;
      out[OFF_QL] = l;
      out[OFF_CL] = l;
    }
  }
}

extern "C" void kernel_launch(void* const* d_in, const int* in_sizes, int n_in,
                              void* d_out, int out_size, void* d_ws, size_t ws_size,
                              hipStream_t stream) {
  const float* x = (const float*)d_in[0];
  const float* emb = (const float*)d_in[1];
  const float* Nin = (const float*)d_in[2];
  const float* Min = (const float*)d_in[3];
  float* out = (float*)d_out;
  float* ws = (float*)d_ws;
  int* idxw = (int*)(ws + WS_IDX);
  float2* cv = (float2*)(ws + WS_CV);
  int2* ci = (int2*)(ws + WS_CI);

  size_t avail = ws_size / 4;
  int P = 0;
  if (avail > (size_t)WS_PART) {
    size_t cap = (avail - WS_PART) / PART_STRIDE;
    P = 256;
    while (P > (int)cap) P >>= 1;
    if (P < 64) P = 0;
  }

  // zero accumulators (ni/eofx for fallback path + loss)
  hipMemsetAsync(ws + WS_NI, 0, (size_t)(WS_ET - WS_NI) * sizeof(float), stream);

  vq_prep<<<2, 256, 0, stream>>>(emb, ws);

  vq_screen<<<(TOKENS / 256) * 2, 256, 0, stream>>>(x, ws, cv, ci);

  vq_resolve<<<TOKENS / 256, 256, 0, stream>>>(
      x, ws, cv, ci, ws + WS_LOSS, out + OFF_Q, out + OFF_IDX, idxw);

  if (P > 0) {
    vq_segsum<<<P, 256, 0, stream>>>(x, idxw, ws + WS_PART, TOKENS / P,
                                     PART_STRIDE, 0);
    vq_reduce<<<(PART_STRIDE + 255) / 256, 256, 0, stream>>>(ws + WS_PART, ws, P);
  } else {
    vq_segsum<<<256, 256, 0, stream>>>(x, idxw, ws + WS_NI, TOKENS / 256, 0, 1);
  }

  vq_final<<<DIM, 512, 0, stream>>>(Nin, Min, ws, out);
}

// Round 5
// 388.353 us; speedup vs baseline: 2.7469x; 1.1190x over previous
//
#include <hip/hip_runtime.h>
#include <hip/hip_bf16.h>
#include <math.h>

#define DIM 64
#define CODES 512
#define TOKENS 262144
#define XELEMS 16777216

#define DECAYF 0.99f
#define OMDECAY 0.01f
#define EPSF 1e-5f

// workspace float offsets
#define WS_CNORM 0            // 512
#define WS_NI    512          // 512
#define WS_EOFX  1024         // 32768
#define WS_LOSS  33792        // 16
#define WS_ET    33808        // 32768 fp32 eT [512][64]
#define WS_IMG   66576        // 32768 floats = 128 KB bf16 hi/lo B image
#define WS_IDX   99344        // 262144 int32
#define WS_PART  361488       // P * PART_STRIDE
#define PART_STRIDE 33280

// output float offsets (reference return order)
#define OFF_Q    0
#define OFF_QL   16777216
#define OFF_IDX  16777217
#define OFF_CL   17039361
#define OFF_ENEW 17039362
#define OFF_NNEW 17072130
#define OFF_MNEW 17072642

typedef __attribute__((ext_vector_type(8))) short bf16x8;
typedef __attribute__((ext_vector_type(4))) float f32x4;

// Truncation hi/lo split: hi = top 16 bits, lo = top 16 bits of (v - hi).
// Residual <= 2^-16 |v| — same error class as RNE hi/lo, far fewer VALU ops.
static __device__ inline void split_bf(float v, short& hi, short& lo) {
  unsigned int b = __float_as_uint(v);
  unsigned int hb = b & 0xffff0000u;
  float lof = v - __uint_as_float(hb);
  hi = (short)(b >> 16);
  lo = (short)(__float_as_uint(lof) >> 16);
}

// Prep: thread per code. eT fp32 rows, cnorm, and the B image:
// [cc(32)][kh(2)][hi|lo][lane(64)*8] shorts (128 KB) so vq_fused's
// ds_read_b128 at lane*16B is conflict-free.
__global__ __launch_bounds__(256) void vq_prep(const float* __restrict__ emb,
                                               float* __restrict__ ws) {
  int c = blockIdx.x * 256 + threadIdx.x;  // 0..511
  unsigned short* img = (unsigned short*)(ws + WS_IMG);
  float* eT = ws + WS_ET;
  int cc = c >> 4;
  int n = c & 15;
  float cn = 0.f;
#pragma unroll
  for (int d0 = 0; d0 < DIM; d0 += 4) {
    float v[4];
#pragma unroll
    for (int u = 0; u < 4; ++u) {
      v[u] = emb[(d0 + u) * CODES + c];
      cn = fmaf(v[u], v[u], cn);
    }
    *(float4*)(eT + (size_t)c * DIM + d0) = make_float4(v[0], v[1], v[2], v[3]);
    int kh = d0 >> 5, kk = d0 & 31, qd = kk >> 3, j0 = kk & 7;
    int lane = qd * 16 + n;
    short hi[4], lo[4];
#pragma unroll
    for (int u = 0; u < 4; ++u) split_bf(v[u], hi[u], lo[u]);
    int base = cc * 2048 + kh * 1024 + lane * 8 + j0;
    *(ushort4*)(img + base) =
        make_ushort4((unsigned short)hi[0], (unsigned short)hi[1],
                     (unsigned short)hi[2], (unsigned short)hi[3]);
    *(ushort4*)(img + base + 512) =
        make_ushort4((unsigned short)lo[0], (unsigned short)lo[1],
                     (unsigned short)lo[2], (unsigned short)lo[3]);
  }
  ws[WS_CNORM + c] = cn;
}

// Fused screen + resolve. Block = 8 waves x 64 tokens = 512 tokens.
// Full 512-code hi/lo B image in LDS (128 KB) -> one-pass compensated-bf16
// MFMA top-2 per token, butterfly merge, then in-wave exact fp32 epilogue
// (cooperative 16-lane dot over the top-2 candidates) writing q/idx/loss.
__global__ __launch_bounds__(512, 2) void vq_fused(
    const float* __restrict__ x, const float* __restrict__ ws,
    float* __restrict__ loss_sum, float* __restrict__ q_out,
    float* __restrict__ idx_out, int* __restrict__ idx_int) {
  __shared__ __align__(16) unsigned short bimg[65536];  // 128 KB
  __shared__ float cn_l[CODES];                          // 2 KB

  const float* eT = ws + WS_ET;

  {
    const float4* src = (const float4*)(ws + WS_IMG);
    float4* dst = (float4*)bimg;
    for (int i = threadIdx.x; i < 8192; i += 512) dst[i] = src[i];
    for (int i = threadIdx.x; i < CODES; i += 512) cn_l[i] = ws[WS_CNORM + i];
  }
  __syncthreads();

  const int lane = threadIdx.x & 63;
  const int wave = threadIdx.x >> 6;
  const int n = lane & 15;
  const int quad = lane >> 4;
  const int t0 = blockIdx.x * 512 + wave * 64;

  // A-fragments hi/lo of -2x for 4 token tiles (truncation split)
  bf16x8 ah[4][2], al[4][2];
#pragma unroll
  for (int tile = 0; tile < 4; ++tile) {
    const float* xr = x + (size_t)(t0 + tile * 16 + n) * DIM + quad * 8;
#pragma unroll
    for (int kh = 0; kh < 2; ++kh) {
      float4 v0 = *(const float4*)(xr + kh * 32);
      float4 v1 = *(const float4*)(xr + kh * 32 + 4);
      float f[8] = {v0.x, v0.y, v0.z, v0.w, v1.x, v1.y, v1.z, v1.w};
#pragma unroll
      for (int j = 0; j < 8; ++j) {
        short hi, lo;
        split_bf(-2.f * f[j], hi, lo);
        ah[tile][kh][j] = hi;
        al[tile][kh][j] = lo;
      }
    }
  }

  float v1[4][4], v2[4][4];
  int i1[4][4], i2[4][4];
#pragma unroll
  for (int tile = 0; tile < 4; ++tile)
#pragma unroll
    for (int r = 0; r < 4; ++r) {
      v1[tile][r] = 1e30f;
      v2[tile][r] = 1e30f;
      i1[tile][r] = 0x3FFFFFFF;
      i2[tile][r] = 0x3FFFFFFF;
    }

  for (int cc = 0; cc < 32; ++cc) {
    const unsigned short* bp = bimg + cc * 2048;
    bf16x8 bh0 = *(const bf16x8*)(bp + lane * 8);
    bf16x8 bl0 = *(const bf16x8*)(bp + 512 + lane * 8);
    bf16x8 bh1 = *(const bf16x8*)(bp + 1024 + lane * 8);
    bf16x8 bl1 = *(const bf16x8*)(bp + 1536 + lane * 8);
    float cnv = cn_l[cc * 16 + n];
    int cid = cc * 16 + n;
#pragma unroll
    for (int tile = 0; tile < 4; ++tile) {
      f32x4 acc = {0.f, 0.f, 0.f, 0.f};
      acc = __builtin_amdgcn_mfma_f32_16x16x32_bf16(ah[tile][0], bh0, acc, 0, 0, 0);
      acc = __builtin_amdgcn_mfma_f32_16x16x32_bf16(al[tile][0], bh0, acc, 0, 0, 0);
      acc = __builtin_amdgcn_mfma_f32_16x16x32_bf16(ah[tile][0], bl0, acc, 0, 0, 0);
      acc = __builtin_amdgcn_mfma_f32_16x16x32_bf16(ah[tile][1], bh1, acc, 0, 0, 0);
      acc = __builtin_amdgcn_mfma_f32_16x16x32_bf16(al[tile][1], bh1, acc, 0, 0, 0);
      acc = __builtin_amdgcn_mfma_f32_16x16x32_bf16(ah[tile][1], bl1, acc, 0, 0, 0);
#pragma unroll
      for (int r = 0; r < 4; ++r) {
        float s = acc[r] + cnv;
        bool c1 = s < v1[tile][r];
        bool c2 = s < v2[tile][r];
        i2[tile][r] = c1 ? i1[tile][r] : (c2 ? cid : i2[tile][r]);
        v2[tile][r] = fminf(fmaxf(s, v1[tile][r]), v2[tile][r]);  // med3
        i1[tile][r] = c1 ? cid : i1[tile][r];
        v1[tile][r] = fminf(s, v1[tile][r]);
      }
    }
  }

  // butterfly top-2 merge across the quad's 16 lanes (all lanes end with result)
#pragma unroll
  for (int m = 1; m < 16; m <<= 1) {
#pragma unroll
    for (int tile = 0; tile < 4; ++tile)
#pragma unroll
      for (int r = 0; r < 4; ++r) {
        float ov1 = __shfl_xor(v1[tile][r], m, 16);
        int oi1 = __shfl_xor(i1[tile][r], m, 16);
        float ov2 = __shfl_xor(v2[tile][r], m, 16);
        int oi2 = __shfl_xor(i2[tile][r], m, 16);
        bool f = ov1 < v1[tile][r];
        float hi = f ? v1[tile][r] : ov1;
        int hii = f ? i1[tile][r] : oi1;
        v1[tile][r] = f ? ov1 : v1[tile][r];
        i1[tile][r] = f ? oi1 : i1[tile][r];
        bool g = ov2 < v2[tile][r];
        float lo2 = g ? ov2 : v2[tile][r];
        int lo2i = g ? oi2 : i2[tile][r];
        bool e2 = hi < lo2;
        v2[tile][r] = e2 ? hi : lo2;
        i2[tile][r] = e2 ? hii : lo2i;
      }
  }

  // Exact fp32 epilogue: 16 lanes per quad cooperatively resolve each token's
  // top-2, write q/idx, accumulate loss. x rows are L1-hot from A-prep.
  float loss = 0.f;
#pragma unroll
  for (int tile = 0; tile < 4; ++tile) {
#pragma unroll
    for (int r = 0; r < 4; ++r) {
      int t = t0 + tile * 16 + quad * 4 + r;
      int c1 = i1[tile][r];
      int c2 = i2[tile][r];
      float4 xv = *(const float4*)(x + (size_t)t * DIM + n * 4);
      float4 e1 = *(const float4*)(eT + (size_t)c1 * DIM + n * 4);
      float4 e2 = *(const float4*)(eT + (size_t)c2 * DIM + n * 4);
      float p1 = xv.x * e1.x;
      p1 = fmaf(xv.y, e1.y, p1);
      p1 = fmaf(xv.z, e1.z, p1);
      p1 = fmaf(xv.w, e1.w, p1);
      float p2 = xv.x * e2.x;
      p2 = fmaf(xv.y, e2.y, p2);
      p2 = fmaf(xv.z, e2.z, p2);
      p2 = fmaf(xv.w, e2.w, p2);
#pragma unroll
      for (int m = 1; m < 16; m <<= 1) {
        p1 += __shfl_xor(p1, m, 16);
        p2 += __shfl_xor(p2, m, 16);
      }
      float d1 = fmaf(-2.f, p1, cn_l[c1]);
      float d2 = fmaf(-2.f, p2, cn_l[c2]);
      bool take2 = (d2 < d1) || (d2 == d1 && c2 < c1);
      int w = take2 ? c2 : c1;
      float4 q = take2 ? e2 : e1;
      *(float4*)(q_out + (size_t)t * DIM + n * 4) = q;
      float u0 = xv.x - q.x, u1 = xv.y - q.y;
      float u2 = xv.z - q.z, u3 = xv.w - q.w;
      loss = fmaf(u0, u0, loss);
      loss = fmaf(u1, u1, loss);
      loss = fmaf(u2, u2, loss);
      loss = fmaf(u3, u3, loss);
      if (n == 0) {
        idx_out[t] = (float)w;
        idx_int[t] = w;
      }
    }
  }
#pragma unroll
  for (int off = 32; off > 0; off >>= 1) loss += __shfl_down(loss, off, 64);
  if (lane == 0) atomicAdd(loss_sum, loss);
}

// Segment sum, LDS privatized, SINGLE pass: full 512x64 fp32 tile (128 KB).
__global__ __launch_bounds__(256, 1) void vq_segsum(
    const float* __restrict__ x, const int* __restrict__ idx,
    float* __restrict__ dest_base, int tokens_per_block, int part_stride,
    int aflush) {
  __shared__ float lds_n[CODES];          // 2 KB
  __shared__ float lds_e[DIM * CODES];    // 128 KB, [d][c]
  int p = blockIdx.x;
  int t0 = p * tokens_per_block;
  float* dest = dest_base + (size_t)p * part_stride;

  {
    float4 z = make_float4(0.f, 0.f, 0.f, 0.f);
    float4* zn = (float4*)lds_n;
    float4* ze = (float4*)lds_e;
    for (int i = threadIdx.x; i < CODES / 4; i += 256) zn[i] = z;
    for (int i = threadIdx.x; i < DIM * CODES / 4; i += 256) ze[i] = z;
  }
  __syncthreads();

  for (int tt = threadIdx.x; tt < tokens_per_block; tt += 256) {
    int t = t0 + tt;
    int bi = idx[t];
    atomicAdd(&lds_n[bi], 1.0f);
    const float4* xp = (const float4*)(x + (size_t)t * DIM);
#pragma unroll
    for (int i = 0; i < DIM / 4; ++i) {
      float4 v = xp[i];
      atomicAdd(&lds_e[(4 * i + 0) * CODES + bi], v.x);
      atomicAdd(&lds_e[(4 * i + 1) * CODES + bi], v.y);
      atomicAdd(&lds_e[(4 * i + 2) * CODES + bi], v.z);
      atomicAdd(&lds_e[(4 * i + 3) * CODES + bi], v.w);
    }
  }
  __syncthreads();

  for (int i = threadIdx.x; i < DIM * CODES; i += 256) {
    float v = lds_e[i];
    if (aflush) {
      if (v != 0.f) atomicAdd(&dest[CODES + i], v);
    } else {
      dest[CODES + i] = v;
    }
  }
  for (int i = threadIdx.x; i < CODES; i += 256) {
    float v = lds_n[i];
    if (aflush) {
      if (v != 0.f) atomicAdd(&dest[i], v);
    } else {
      dest[i] = v;
    }
  }
}

__global__ __launch_bounds__(256) void vq_reduce(const float* __restrict__ part,
                                                 float* __restrict__ ws, int P) {
  int i = blockIdx.x * 256 + threadIdx.x;
  if (i >= PART_STRIDE) return;
  float a0 = 0.f, a1 = 0.f, a2 = 0.f, a3 = 0.f;
  int p = 0;
  for (; p + 3 < P; p += 4) {
    a0 += part[(size_t)(p + 0) * PART_STRIDE + i];
    a1 += part[(size_t)(p + 1) * PART_STRIDE + i];
    a2 += part[(size_t)(p + 2) * PART_STRIDE + i];
    a3 += part[(size_t)(p + 3) * PART_STRIDE + i];
  }
  for (; p < P; ++p) a0 += part[(size_t)p * PART_STRIDE + i];
  ws[WS_NI + i] = (a0 + a1) + (a2 + a3);
}

// EMA update + losses. Grid = DIM blocks, one thread per code.
__global__ __launch_bounds__(512) void vq_final(const float* __restrict__ Nin,
                                                const float* __restrict__ Min,
                                                const float* __restrict__ ws,
                                                float* __restrict__ out) {
  __shared__ float red[512];
  int c = threadIdx.x;
  int d = blockIdx.x;
  float niv = ws[WS_NI + c];
  float Nn = Nin[c] * DECAYF + OMDECAY * niv;
  red[c] = Nn;
  __syncthreads();
#pragma unroll
  for (int s = 256; s > 0; s >>= 1) {
    if (c < s) red[c] += red[c + s];
    __syncthreads();
  }
  float nsum = red[0];
  float Nsm = (Nn + EPSF) / (nsum + (float)CODES * EPSF) * nsum;
  float m = Min[d * CODES + c] * DECAYF + OMDECAY * ws[WS_EOFX + d * CODES + c];
  out[OFF_MNEW + d * CODES + c] = m;
  out[OFF_ENEW + d * CODES + c] = m / Nsm;
  if (d == 0) {
    out[OFF_NNEW + c] = Nn;
    if (c == 0) {
      float l = ws[WS_LOSS] / (float)XELEMS;
      out[OFF_QL] = l;
      out[OFF_CL] = l;
    }
  }
}

extern "C" void kernel_launch(void* const* d_in, const int* in_sizes, int n_in,
                              void* d_out, int out_size, void* d_ws, size_t ws_size,
                              hipStream_t stream) {
  const float* x = (const float*)d_in[0];
  const float* emb = (const float*)d_in[1];
  const float* Nin = (const float*)d_in[2];
  const float* Min = (const float*)d_in[3];
  float* out = (float*)d_out;
  float* ws = (float*)d_ws;
  int* idxw = (int*)(ws + WS_IDX);

  size_t avail = ws_size / 4;
  int P = 0;
  if (avail > (size_t)WS_PART) {
    size_t cap = (avail - WS_PART) / PART_STRIDE;
    P = 256;
    while (P > (int)cap) P >>= 1;
    if (P < 64) P = 0;
  }

  // zero loss + (fallback path) ni/eofx accumulators
  hipMemsetAsync(ws + WS_NI, 0, (size_t)(WS_ET - WS_NI) * sizeof(float), stream);

  vq_prep<<<2, 256, 0, stream>>>(emb, ws);

  vq_fused<<<TOKENS / 512, 512, 0, stream>>>(
      x, ws, ws + WS_LOSS, out + OFF_Q, out + OFF_IDX, idxw);

  if (P > 0) {
    vq_segsum<<<P, 256, 0, stream>>>(x, idxw, ws + WS_PART, TOKENS / P,
                                     PART_STRIDE, 0);
    vq_reduce<<<(PART_STRIDE + 255) / 256, 256, 0, stream>>>(ws + WS_PART, ws, P);
  } else {
    vq_segsum<<<256, 256, 0, stream>>>(x, idxw, ws + WS_NI, TOKENS / 256, 0, 1);
  }

  vq_final<<<DIM, 512, 0, stream>>>(Nin, Min, ws, out);
}

// Round 6
// 361.172 us; speedup vs baseline: 2.9536x; 1.0753x over previous
//
#include <hip/hip_runtime.h>
#include <hip/hip_bf16.h>
#include <math.h>

#define DIM 64
#define CODES 512
#define TOKENS 262144
#define XELEMS 16777216

#define DECAYF 0.99f
#define OMDECAY 0.01f
#define EPSF 1e-5f

// workspace float offsets
#define WS_CNORM 0            // 512
#define WS_NI    512          // 512
#define WS_EOFX  1024         // 32768
#define WS_LOSS  33792        // 16
#define WS_ET    33808        // 32768 fp32 eT [512][64]
#define WS_IMG   66576        // 32768 floats = 128 KB bf16 hi/lo B image
#define WS_PART  99344        // 512 partials * PART_STRIDE
#define PART_STRIDE 33280
#define NPART 512

// output float offsets (reference return order)
#define OFF_Q    0
#define OFF_QL   16777216
#define OFF_IDX  16777217
#define OFF_CL   17039361
#define OFF_ENEW 17039362
#define OFF_NNEW 17072130
#define OFF_MNEW 17072642

typedef __attribute__((ext_vector_type(8))) short bf16x8;
typedef __attribute__((ext_vector_type(4))) float f32x4;

// Truncation hi/lo split: hi = top 16 bits, lo = top 16 bits of (v - hi).
// hi+lo = v with residual <= 2^-16 * 2|v|.
static __device__ inline void split_bf(float v, short& hi, short& lo) {
  unsigned int b = __float_as_uint(v);
  unsigned int hb = b & 0xffff0000u;
  float lof = v - __uint_as_float(hb);
  hi = (short)(b >> 16);
  lo = (short)(__float_as_uint(lof) >> 16);
}
static __device__ inline float bf2f(short s) {
  unsigned int u = ((unsigned int)(unsigned short)s) << 16;
  return __uint_as_float(u);
}

// Prep: thread per code. eT fp32 rows, cnorm, and the B image:
// [cc(32)][kh(2)][hi|lo][lane(64)*8] shorts (128 KB), conflict-free ds_read_b128.
__global__ __launch_bounds__(256) void vq_prep(const float* __restrict__ emb,
                                               float* __restrict__ ws) {
  int c = blockIdx.x * 256 + threadIdx.x;  // 0..511
  unsigned short* img = (unsigned short*)(ws + WS_IMG);
  float* eT = ws + WS_ET;
  int cc = c >> 4;
  int n = c & 15;
  float cn = 0.f;
#pragma unroll
  for (int d0 = 0; d0 < DIM; d0 += 4) {
    float v[4];
#pragma unroll
    for (int u = 0; u < 4; ++u) {
      v[u] = emb[(d0 + u) * CODES + c];
      cn = fmaf(v[u], v[u], cn);
    }
    *(float4*)(eT + (size_t)c * DIM + d0) = make_float4(v[0], v[1], v[2], v[3]);
    int kh = d0 >> 5, kk = d0 & 31, qd = kk >> 3, j0 = kk & 7;
    int lane = qd * 16 + n;
    short hi[4], lo[4];
#pragma unroll
    for (int u = 0; u < 4; ++u) split_bf(v[u], hi[u], lo[u]);
    int base = cc * 2048 + kh * 1024 + lane * 8 + j0;
    *(ushort4*)(img + base) =
        make_ushort4((unsigned short)hi[0], (unsigned short)hi[1],
                     (unsigned short)hi[2], (unsigned short)hi[3]);
    *(ushort4*)(img + base + 512) =
        make_ushort4((unsigned short)lo[0], (unsigned short)lo[1],
                     (unsigned short)lo[2], (unsigned short)lo[3]);
  }
  ws[WS_CNORM + c] = cn;
}

// Fused screen + resolve + segment-sum. Block = 8 waves x 64 tokens.
// Phase 1 (bimg/cn_l live): compensated-bf16 MFMA screen with PACKED-FLOAT
//   top-2 (code id in low 9 mantissa bits), butterfly merge, exact fp32
//   epilogue writing q/idx/loss + per-block winner table.
// Phase 2 (bimg dead, LDS reused): scatter x (rebuilt from ah/al regs) into a
//   [64][513]-padded LDS tile by winner code, flush per-block partial.
__global__ __launch_bounds__(512, 2) void vq_fused(
    const float* __restrict__ x, const float* __restrict__ ws,
    float* __restrict__ loss_sum, float* __restrict__ q_out,
    float* __restrict__ idx_out, float* __restrict__ part_base, int aflush,
    float* __restrict__ ws_acc) {
  __shared__ __align__(16) unsigned char smem[135424];
  unsigned short* bimg = (unsigned short*)smem;          // [0, 131072)
  float* cn_l = (float*)(smem + 131072);                 // [131072, 133120)
  int* win_l = (int*)(smem + 133376);                    // [133376, 135424)
  float* lds_n = (float*)smem;                           // phase2 [0, 2048)
  float* lds_e = (float*)(smem + 2048);                  // phase2 [2048, 133376)

  const float* eT = ws + WS_ET;

  {
    const float4* src = (const float4*)(ws + WS_IMG);
    float4* dst = (float4*)bimg;
    for (int i = threadIdx.x; i < 8192; i += 512) dst[i] = src[i];
    for (int i = threadIdx.x; i < CODES; i += 512) cn_l[i] = ws[WS_CNORM + i];
  }
  __syncthreads();

  const int lane = threadIdx.x & 63;
  const int wave = threadIdx.x >> 6;
  const int n = lane & 15;
  const int quad = lane >> 4;
  const int t0 = blockIdx.x * 512 + wave * 64;

  // A-fragments hi/lo of -2x for 4 token tiles (stay live through phase 2)
  bf16x8 ah[4][2], al[4][2];
#pragma unroll
  for (int tile = 0; tile < 4; ++tile) {
    const float* xr = x + (size_t)(t0 + tile * 16 + n) * DIM + quad * 8;
#pragma unroll
    for (int kh = 0; kh < 2; ++kh) {
      float4 v0 = *(const float4*)(xr + kh * 32);
      float4 v1v = *(const float4*)(xr + kh * 32 + 4);
      float f[8] = {v0.x, v0.y, v0.z, v0.w, v1v.x, v1v.y, v1v.z, v1v.w};
#pragma unroll
      for (int j = 0; j < 8; ++j) {
        short hi, lo;
        split_bf(-2.f * f[j], hi, lo);
        ah[tile][kh][j] = hi;
        al[tile][kh][j] = lo;
      }
    }
  }

  // packed (value|idx) top-2 registers
  const float INITP = __uint_as_float((__float_as_uint(1e30f) & 0xFFFFFE00u) | 511u);
  float v1[4][4], v2[4][4];
#pragma unroll
  for (int tile = 0; tile < 4; ++tile)
#pragma unroll
    for (int r = 0; r < 4; ++r) {
      v1[tile][r] = INITP;
      v2[tile][r] = INITP;
    }

  for (int cc = 0; cc < 32; ++cc) {
    const unsigned short* bp = bimg + cc * 2048;
    bf16x8 bh0 = *(const bf16x8*)(bp + lane * 8);
    bf16x8 bl0 = *(const bf16x8*)(bp + 512 + lane * 8);
    bf16x8 bh1 = *(const bf16x8*)(bp + 1024 + lane * 8);
    bf16x8 bl1 = *(const bf16x8*)(bp + 1536 + lane * 8);
    float cnv = cn_l[cc * 16 + n];
    unsigned int cid = (unsigned int)(cc * 16 + n);
#pragma unroll
    for (int tile = 0; tile < 4; ++tile) {
      f32x4 acc = {0.f, 0.f, 0.f, 0.f};
      acc = __builtin_amdgcn_mfma_f32_16x16x32_bf16(ah[tile][0], bh0, acc, 0, 0, 0);
      acc = __builtin_amdgcn_mfma_f32_16x16x32_bf16(al[tile][0], bh0, acc, 0, 0, 0);
      acc = __builtin_amdgcn_mfma_f32_16x16x32_bf16(ah[tile][0], bl0, acc, 0, 0, 0);
      acc = __builtin_amdgcn_mfma_f32_16x16x32_bf16(ah[tile][1], bh1, acc, 0, 0, 0);
      acc = __builtin_amdgcn_mfma_f32_16x16x32_bf16(al[tile][1], bh1, acc, 0, 0, 0);
      acc = __builtin_amdgcn_mfma_f32_16x16x32_bf16(ah[tile][1], bl1, acc, 0, 0, 0);
#pragma unroll
      for (int r = 0; r < 4; ++r) {
        float s = acc[r] + cnv;
        float sp = __uint_as_float((__float_as_uint(s) & 0xFFFFFE00u) | cid);
        float o1 = v1[tile][r];
        v2[tile][r] = __builtin_amdgcn_fmed3f(sp, o1, v2[tile][r]);
        v1[tile][r] = fminf(sp, o1);
      }
    }
  }

  // butterfly top-2 merge across the quad's 16 lanes (packed floats)
#pragma unroll
  for (int m = 1; m < 16; m <<= 1) {
#pragma unroll
    for (int tile = 0; tile < 4; ++tile)
#pragma unroll
      for (int r = 0; r < 4; ++r) {
        float o1 = __shfl_xor(v1[tile][r], m, 16);
        float o2 = __shfl_xor(v2[tile][r], m, 16);
        float a = v1[tile][r];
        v1[tile][r] = fminf(a, o1);
        v2[tile][r] = fminf(fminf(v2[tile][r], o2), fmaxf(a, o1));
      }
  }

  // Exact fp32 epilogue: 16 lanes per quad resolve each token's top-2,
  // write q/idx/loss and the winner table for phase 2.
  float loss = 0.f;
#pragma unroll
  for (int tile = 0; tile < 4; ++tile) {
#pragma unroll
    for (int r = 0; r < 4; ++r) {
      int t = t0 + tile * 16 + quad * 4 + r;
      int c1 = (int)(__float_as_uint(v1[tile][r]) & 511u);
      int c2 = (int)(__float_as_uint(v2[tile][r]) & 511u);
      float4 xv = *(const float4*)(x + (size_t)t * DIM + n * 4);
      float4 e1 = *(const float4*)(eT + (size_t)c1 * DIM + n * 4);
      float4 e2 = *(const float4*)(eT + (size_t)c2 * DIM + n * 4);
      float p1 = xv.x * e1.x;
      p1 = fmaf(xv.y, e1.y, p1);
      p1 = fmaf(xv.z, e1.z, p1);
      p1 = fmaf(xv.w, e1.w, p1);
      float p2 = xv.x * e2.x;
      p2 = fmaf(xv.y, e2.y, p2);
      p2 = fmaf(xv.z, e2.z, p2);
      p2 = fmaf(xv.w, e2.w, p2);
#pragma unroll
      for (int m = 1; m < 16; m <<= 1) {
        p1 += __shfl_xor(p1, m, 16);
        p2 += __shfl_xor(p2, m, 16);
      }
      float d1 = fmaf(-2.f, p1, cn_l[c1]);
      float d2 = fmaf(-2.f, p2, cn_l[c2]);
      bool take2 = (d2 < d1) || (d2 == d1 && c2 < c1);
      int w = take2 ? c2 : c1;
      float4 q = take2 ? e2 : e1;
      *(float4*)(q_out + (size_t)t * DIM + n * 4) = q;
      float u0 = xv.x - q.x, u1 = xv.y - q.y;
      float u2 = xv.z - q.z, u3 = xv.w - q.w;
      loss = fmaf(u0, u0, loss);
      loss = fmaf(u1, u1, loss);
      loss = fmaf(u2, u2, loss);
      loss = fmaf(u3, u3, loss);
      if (n == 0) {
        idx_out[t] = (float)w;
        win_l[wave * 64 + tile * 16 + quad * 4 + r] = w;
      }
    }
  }
#pragma unroll
  for (int off = 32; off > 0; off >>= 1) loss += __shfl_down(loss, off, 64);
  if (lane == 0) atomicAdd(loss_sum, loss);

  // ---- Phase 2: segment sum over this block's 512 tokens ----
  __syncthreads();  // bimg/cn_l dead; win_l preserved (outside zero range)
  {
    float4 z = make_float4(0.f, 0.f, 0.f, 0.f);
    float4* zp = (float4*)smem;
    for (int i = threadIdx.x; i < 133376 / 16; i += 512) zp[i] = z;
  }
  __syncthreads();

#pragma unroll
  for (int tile = 0; tile < 4; ++tile) {
    int wbi = win_l[wave * 64 + tile * 16 + n];
    if (quad == 0) atomicAdd(&lds_n[wbi], 1.0f);
#pragma unroll
    for (int kh = 0; kh < 2; ++kh) {
#pragma unroll
      for (int j = 0; j < 8; ++j) {
        float xk = -0.5f * (bf2f(ah[tile][kh][j]) + bf2f(al[tile][kh][j]));
        int k = kh * 32 + quad * 8 + j;
        atomicAdd(&lds_e[k * 513 + wbi], xk);  // stride 513: quads hit 4 banks
      }
    }
  }
  __syncthreads();

  if (aflush) {
    for (int i = threadIdx.x; i < CODES; i += 512) {
      float v = lds_n[i];
      if (v != 0.f) atomicAdd(&ws_acc[WS_NI + i], v);
    }
    for (int i = threadIdx.x; i < DIM * CODES; i += 512) {
      int k = i >> 9, c = i & 511;
      float v = lds_e[k * 513 + c];
      if (v != 0.f) atomicAdd(&ws_acc[WS_EOFX + i], v);
    }
  } else {
    float* dest = part_base + (size_t)blockIdx.x * PART_STRIDE;
    for (int i = threadIdx.x; i < CODES; i += 512) dest[i] = lds_n[i];
    for (int i = threadIdx.x; i < DIM * CODES; i += 512) {
      int k = i >> 9, c = i & 511;
      dest[CODES + i] = lds_e[k * 513 + c];
    }
  }
}

// Deterministic reduction of NPART partials -> ws[WS_NI ..]
__global__ __launch_bounds__(256) void vq_reduce(const float* __restrict__ part,
                                                 float* __restrict__ ws, int P) {
  int i = blockIdx.x * 256 + threadIdx.x;
  if (i >= PART_STRIDE) return;
  float a0 = 0.f, a1 = 0.f, a2 = 0.f, a3 = 0.f;
  int p = 0;
  for (; p + 3 < P; p += 4) {
    a0 += part[(size_t)(p + 0) * PART_STRIDE + i];
    a1 += part[(size_t)(p + 1) * PART_STRIDE + i];
    a2 += part[(size_t)(p + 2) * PART_STRIDE + i];
    a3 += part[(size_t)(p + 3) * PART_STRIDE + i];
  }
  for (; p < P; ++p) a0 += part[(size_t)p * PART_STRIDE + i];
  ws[WS_NI + i] = (a0 + a1) + (a2 + a3);
}

// EMA update + losses. Grid = DIM blocks, one thread per code.
__global__ __launch_bounds__(512) void vq_final(const float* __restrict__ Nin,
                                                const float* __restrict__ Min,
                                                const float* __restrict__ ws,
                                                float* __restrict__ out) {
  __shared__ float red[512];
  int c = threadIdx.x;
  int d = blockIdx.x;
  float niv = ws[WS_NI + c];
  float Nn = Nin[c] * DECAYF + OMDECAY * niv;
  red[c] = Nn;
  __syncthreads();
#pragma unroll
  for (int s = 256; s > 0; s >>= 1) {
    if (c < s) red[c] += red[c + s];
    __syncthreads();
  }
  float nsum = red[0];
  float Nsm = (Nn + EPSF) / (nsum + (float)CODES * EPSF) * nsum;
  float m = Min[d * CODES + c] * DECAYF + OMDECAY * ws[WS_EOFX + d * CODES + c];
  out[OFF_MNEW + d * CODES + c] = m;
  out[OFF_ENEW + d * CODES + c] = m / Nsm;
  if (d == 0) {
    out[OFF_NNEW + c] = Nn;
    if (c == 0) {
      float l = ws[WS_LOSS] / (float)XELEMS;
      out[OFF_QL] = l;
      out[OFF_CL] = l;
    }
  }
}

extern "C" void kernel_launch(void* const* d_in, const int* in_sizes, int n_in,
                              void* d_out, int out_size, void* d_ws, size_t ws_size,
                              hipStream_t stream) {
  const float* x = (const float*)d_in[0];
  const float* emb = (const float*)d_in[1];
  const float* Nin = (const float*)d_in[2];
  const float* Min = (const float*)d_in[3];
  float* out = (float*)d_out;
  float* ws = (float*)d_ws;

  size_t avail = ws_size / 4;
  int aflush = (avail < (size_t)WS_PART + (size_t)NPART * PART_STRIDE) ? 1 : 0;

  // zero ni/eofx/loss (loss always needed; ni/eofx needed for aflush path)
  hipMemsetAsync(ws + WS_NI, 0, (size_t)(WS_ET - WS_NI) * sizeof(float), stream);

  vq_prep<<<2, 256, 0, stream>>>(emb, ws);

  vq_fused<<<TOKENS / 512, 512, 0, stream>>>(
      x, ws, ws + WS_LOSS, out + OFF_Q, out + OFF_IDX, ws + WS_PART, aflush, ws);

  if (!aflush) {
    vq_reduce<<<(PART_STRIDE + 255) / 256, 256, 0, stream>>>(ws + WS_PART, ws,
                                                             NPART);
  }

  vq_final<<<DIM, 512, 0, stream>>>(Nin, Min, ws, out);
}